// Round 6
// baseline (139.388 us; speedup 1.0000x reference)
//
#include <hip/hip_runtime.h>
#include <math.h>

// SpheresRasterizer: B=1, N=1024, H=W=256, K=8.
// Round 6: DIAGNOSTIC. Real output path = round-5 kernel (MODE 0, unchanged).
// Extra amplified probe dispatches (x16 reps, writing to d_ws) to surface
// per-phase cost + VGPR/VALUBusy in rocprof top-5:
//   MODE 1: phase 1 only (transform+cull+compact+sentinel)
//   MODE 3: phase 1 with v_rcp_f32 fast division (probe: are divides the sink?)
//   MODE 2: full kernel
// (MODE 1/3 keep work live by reading cmp[0]/cidx[0]/M back to d_ws after the
//  barrier — compaction writes are dynamically addressed, so no DCE.)

#define KPP 8
#define BW  8

template<int MODE, int REPS>
__global__ __launch_bounds__(256) void sphere_raster_kernel(
    const float* __restrict__ points,   // B*N*3
    const float* __restrict__ radius,   // B*N
    const float* __restrict__ w2v,      // B*16
    const float* __restrict__ proj,     // B*16
    float* __restrict__ out,            // 3 * B*H*W*KPP floats (or ws scratch)
    int B, int N, int H, int W)
{
    extern __shared__ char smem[];
    float4* cmp  = (float4*)smem;                                     // N+2*BW
    int*    cidx = (int*)(smem + (size_t)(N + 2 * BW) * sizeof(float4));
    __shared__ int wsum[4];

    const int TS = 16;
    const int tilesX = W / TS;
    const int tile   = blockIdx.x % (tilesX * (H / TS));
    const int b      = blockIdx.x / (tilesX * (H / TS));
    const int tx0    = (tile % tilesX) * TS;
    const int ty0    = (tile / tilesX) * TS;
    const int j      = tx0 + (threadIdx.x & (TS - 1));
    const int i      = ty0 + (threadIdx.x >> 4);
    const int lane   = threadIdx.x & 63;
    const int wid    = threadIdx.x >> 6;

    const float* M1 = w2v  + (size_t)b * 16;
    const float* M2 = proj + (size_t)b * 16;

    const double halfd = 1.0 - 1.0 / (double)W;
    const double step  = 2.0 * halfd / (double)(W - 1);
    const float px = (float)(halfd - (double)j * step);
    const float py = (float)(halfd - (double)i * step);

    const float cx = (float)(halfd - ((double)tx0 + (TS - 1) * 0.5) * step);
    const float cy = (float)(halfd - ((double)ty0 + (TS - 1) * 0.5) * step);
    const float hext = (float)(((TS - 1) * 0.5 + 1.0) * step);

    for (int rep = 0; rep < REPS; ++rep) {
        __syncthreads();   // LDS reuse across reps (values identical anyway)

        // ---- Phase 1: transform 4 points/thread, cull to tile box ----
        const int t0 = threadIdx.x * 4;
        float4 P[4];
        int keep[4];
        int c = 0;

        const float4* pv = (const float4*)(points + ((size_t)b * N + t0) * 3);
        float4 q0 = pv[0], q1 = pv[1], q2 = pv[2];
        float4 rr = *(const float4*)(radius + (size_t)b * N + t0);
        float xs[4] = {q0.x, q0.w, q1.z, q2.y};
        float ys[4] = {q0.y, q1.x, q1.w, q2.z};
        float zs[4] = {q0.z, q1.y, q2.x, q2.w};
        float rv[4] = {rr.x, rr.y, rr.z, rr.w};

#pragma unroll
        for (int s = 0; s < 4; ++s) {
            float x = xs[s], y = ys[s], z = zs[s];
            float vx = ((x * M1[0] + y * M1[4]) + z * M1[8])  + M1[12];
            float vy = ((x * M1[1] + y * M1[5]) + z * M1[9])  + M1[13];
            float vz = ((x * M1[2] + y * M1[6]) + z * M1[10]) + M1[14];
            float vw = ((x * M1[3] + y * M1[7]) + z * M1[11]) + M1[15];
            float w1 = (fabsf(vw) < 1e-8f) ? 1e-8f : vw;
            if (MODE == 3) {
                float i1 = __builtin_amdgcn_rcpf(w1);      // probe-only numerics
                vx *= i1; vy *= i1; vz *= i1;
            } else {
                vx /= w1; vy /= w1; vz /= w1;
            }
            float sx = ((vx * M2[0] + vy * M2[4]) + vz * M2[8])  + M2[12];
            float sy = ((vx * M2[1] + vy * M2[5]) + vz * M2[9])  + M2[13];
            float sw = ((vx * M2[3] + vy * M2[7]) + vz * M2[11]) + M2[15];
            float w2 = (fabsf(sw) < 1e-8f) ? 1e-8f : sw;
            if (MODE == 3) {
                float i2 = __builtin_amdgcn_rcpf(w2);
                sx *= i2; sy *= i2;
            } else {
                sx /= w2; sy /= w2;
            }
            float r = rv[s];
            float r2eff = (vz > 0.0f) ? r * r : -1.0f;
            float dxm = fmaxf(0.0f, fabsf(sx - cx) - hext);
            float dym = fmaxf(0.0f, fabsf(sy - cy) - hext);
            float dmin2 = dxm * dxm + dym * dym;
            keep[s] = (dmin2 <= r2eff + 1e-6f) ? 1 : 0;
            P[s] = make_float4(sx, sy, vz, r2eff);
            c += keep[s];
        }

        // ---- order-preserving compaction ----
        int pre = c;
#pragma unroll
        for (int d = 1; d < 64; d <<= 1) {
            int v = __shfl_up(pre, d);
            if (lane >= d) pre += v;
        }
        if (lane == 63) wsum[wid] = pre;
        __syncthreads();
        int wbase = 0, M = 0;
#pragma unroll
        for (int w = 0; w < 4; ++w) {
            int s = wsum[w];
            if (w < wid) wbase += s;
            M += s;
        }
        int pos = wbase + (pre - c);
#pragma unroll
        for (int s = 0; s < 4; ++s) {
            if (keep[s]) { cmp[pos] = P[s]; cidx[pos] = t0 + s; ++pos; }
        }

        const int Mpad = (M + 2 * BW - 1) & ~(2 * BW - 1);
        if (threadIdx.x < Mpad - M) {
            cmp[M + threadIdx.x]  = make_float4(0.0f, 0.0f, 0.0f, -1.0f);
            cidx[M + threadIdx.x] = -1;
        }
        __syncthreads();

        if (MODE == 1 || MODE == 3) {
            // phase-1-only probe: read back LDS so nothing is dead
            if (threadIdx.x == 0) {
                float4 c0 = cmp[0];
                float4* o4 = (float4*)out;
                o4[tile * 2]     = c0;
                o4[tile * 2 + 1] = make_float4((float)M, (float)cidx[0], c0.z, c0.w);
            }
            continue;
        }

        // ---- Phase 2: double-buffered 8-wide batched scan ----
        float zb[KPP]; int id[KPP]; float dd[KPP];
#pragma unroll
        for (int k = 0; k < KPP; ++k) { zb[k] = INFINITY; id[k] = -1; dd[k] = -1.0f; }

        auto process = [&](const float4* pp, const int* ii) {
#pragma unroll
            for (int u = 0; u < BW; ++u) {
                float dx = pp[u].x - px;
                float dy = pp[u].y - py;
                float dist2 = __fadd_rn(__fmul_rn(dx, dx), __fmul_rn(dy, dy));
                if ((dist2 <= pp[u].w) && (pp[u].z < zb[KPP - 1])) {
                    float zc = pp[u].z; int ic = ii[u]; float dc = dist2;
#pragma unroll
                    for (int k2 = 0; k2 < KPP; ++k2) {
                        bool lt = (zc < zb[k2]);
                        float tz = zb[k2]; int ti = id[k2]; float td = dd[k2];
                        if (lt) { zb[k2] = zc; id[k2] = ic; dd[k2] = dc; zc = tz; ic = ti; dc = td; }
                    }
                }
            }
        };

        float4 pa[BW]; int ia[BW];
        float4 pb[BW]; int ib[BW];

#pragma unroll
        for (int u = 0; u < BW; ++u) pa[u] = cmp[u];
        {
            int4 t4a = *(const int4*)&cidx[0];
            int4 t4b = *(const int4*)&cidx[4];
            ia[0]=t4a.x; ia[1]=t4a.y; ia[2]=t4a.z; ia[3]=t4a.w;
            ia[4]=t4b.x; ia[5]=t4b.y; ia[6]=t4b.z; ia[7]=t4b.w;
        }

        for (int n = 0; n < Mpad; n += 2 * BW) {
#pragma unroll
            for (int u = 0; u < BW; ++u) pb[u] = cmp[n + BW + u];
            {
                int4 t4a = *(const int4*)&cidx[n + BW];
                int4 t4b = *(const int4*)&cidx[n + BW + 4];
                ib[0]=t4a.x; ib[1]=t4a.y; ib[2]=t4a.z; ib[3]=t4a.w;
                ib[4]=t4b.x; ib[5]=t4b.y; ib[6]=t4b.z; ib[7]=t4b.w;
            }
            process(pa, ia);
            if (n + 2 * BW < Mpad) {
#pragma unroll
                for (int u = 0; u < BW; ++u) pa[u] = cmp[n + 2 * BW + u];
                int4 t4a = *(const int4*)&cidx[n + 2 * BW];
                int4 t4b = *(const int4*)&cidx[n + 2 * BW + 4];
                ia[0]=t4a.x; ia[1]=t4a.y; ia[2]=t4a.z; ia[3]=t4a.w;
                ia[4]=t4b.x; ia[5]=t4b.y; ia[6]=t4b.z; ia[7]=t4b.w;
            }
            process(pb, ib);
        }

        // ---- Phase 3: write outputs ----
        const size_t pix   = ((size_t)b * H + i) * W + j;
        const size_t plane = (size_t)B * H * W * KPP;
        float vidx[KPP], vzbf[KPP], vdst[KPP];
#pragma unroll
        for (int k = 0; k < KPP; ++k) {
            bool valid = (zb[k] != INFINITY);
            vidx[k] = valid ? (float)id[k] : -1.0f;
            vzbf[k] = valid ? zb[k]        : -1.0f;
            vdst[k] = valid ? dd[k]        : -1.0f;
        }
        float* oidx = out + pix * KPP;
        float* ozbf = out + plane + pix * KPP;
        float* odst = out + 2 * plane + pix * KPP;
        *(float4*)(oidx)     = make_float4(vidx[0], vidx[1], vidx[2], vidx[3]);
        *(float4*)(oidx + 4) = make_float4(vidx[4], vidx[5], vidx[6], vidx[7]);
        *(float4*)(ozbf)     = make_float4(vzbf[0], vzbf[1], vzbf[2], vzbf[3]);
        *(float4*)(ozbf + 4) = make_float4(vzbf[4], vzbf[5], vzbf[6], vzbf[7]);
        *(float4*)(odst)     = make_float4(vdst[0], vdst[1], vdst[2], vdst[3]);
        *(float4*)(odst + 4) = make_float4(vdst[4], vdst[5], vdst[6], vdst[7]);
    }
}

extern "C" void kernel_launch(void* const* d_in, const int* in_sizes, int n_in,
                              void* d_out, int out_size, void* d_ws, size_t ws_size,
                              hipStream_t stream) {
    const float* points = (const float*)d_in[0];
    const float* radius = (const float*)d_in[1];
    const float* w2v    = (const float*)d_in[2];
    const float* proj   = (const float*)d_in[3];
    int B = in_sizes[2] / 16;
    if (B < 1) B = 1;
    int N = in_sizes[1] / B;
    int HW = out_size / (3 * B * KPP);
    int H = 1;
    while ((H + 1) * (H + 1) <= HW) ++H;
    int W = H;

    int tiles = (W / 16) * (H / 16);
    dim3 grid(B * tiles);
    dim3 block(256);
    size_t shmem = (size_t)(N + 2 * BW) * (sizeof(float4) + sizeof(int));

    // Real output (round-5 behavior, unchanged)
    sphere_raster_kernel<0, 1><<<grid, block, shmem, stream>>>(
        points, radius, w2v, proj, (float*)d_out, B, N, H, W);

    // Diagnostics -> d_ws (amplified x16 so they surface in rocprof top-5)
    float* ws = (float*)d_ws;
    sphere_raster_kernel<1, 16><<<grid, block, shmem, stream>>>(
        points, radius, w2v, proj, ws, B, N, H, W);
    sphere_raster_kernel<3, 16><<<grid, block, shmem, stream>>>(
        points, radius, w2v, proj, ws + (1 << 16), B, N, H, W);
    sphere_raster_kernel<2, 16><<<grid, block, shmem, stream>>>(
        points, radius, w2v, proj, ws + (1 << 20), B, N, H, W);
}

// Round 7
// 22.689 us; speedup vs baseline: 6.1435x; 6.1435x over previous
//
#include <hip/hip_runtime.h>
#include <math.h>

// SpheresRasterizer: B=1, N=1024, H=W=256, K=8.
// Round 7: (a) 1024-thread blocks, 4-way point-sliced scan + LDS merge
//          (worst-tile insertion cost /4, bit-identical results);
//          (b) 4 empty floor-probe dispatches to measure launch floor F:
//          dur_total = T_main + 4F.  Probes write only d_ws.
//
// Slicing correctness: compacted list is in ascending point index; slices
// take CONTIGUOUS chunks, so slice s candidates all have larger indices than
// slice s-1. Each slice's top-8 is z-ascending (ties index-ascending). Merge
// inserts slices 1..3 in order with strict '<', reproducing the exact
// sequential-scan result (no float arithmetic in merge).

#define KPP 8
#define TS  16

__global__ __launch_bounds__(1024, 4) void sphere_raster_kernel(
    const float* __restrict__ points,   // B*N*3
    const float* __restrict__ radius,   // B*N
    const float* __restrict__ w2v,      // B*16
    const float* __restrict__ proj,     // B*16
    float* __restrict__ out,            // 3 * B*H*W*KPP floats
    int B, int N, int H, int W)
{
    extern __shared__ char smem[];
    float4* cmp  = (float4*)smem;                                  // N+64
    int*    cidx = (int*)(smem + (size_t)(N + 64) * sizeof(float4));
    // merge buffers alias cmp/cidx (only used after the post-scan barrier)
    float*  mz   = (float*)smem;            // [8][256] f32
    int*    mi   = (int*)(smem + 8192);     // [8][256] i32
    float*  md   = (float*)(smem + 16384);  // [8][256] f32
    __shared__ int wsum[16];

    const int tid  = threadIdx.x;
    const int p    = tid & 255;          // pixel within tile
    const int sl   = tid >> 8;           // point slice 0..3 (= wave quad)
    const int lane = tid & 63;
    const int wid  = tid >> 6;           // 0..15

    const int tilesPer = (W / TS) * (H / TS);
    const int tile = blockIdx.x % tilesPer;
    const int b    = blockIdx.x / tilesPer;
    const int tx0  = (tile % (W / TS)) * TS;
    const int ty0  = (tile / (W / TS)) * TS;
    const int j    = tx0 + (p & (TS - 1));
    const int i    = ty0 + (p >> 4);

    const float* M1 = w2v  + (size_t)b * 16;
    const float* M2 = proj + (size_t)b * 16;

    const double halfd = 1.0 - 1.0 / (double)W;
    const double step  = 2.0 * halfd / (double)(W - 1);
    const float px = (float)(halfd - (double)j * step);
    const float py = (float)(halfd - (double)i * step);

    const float cx = (float)(halfd - ((double)tx0 + (TS - 1) * 0.5) * step);
    const float cy = (float)(halfd - ((double)ty0 + (TS - 1) * 0.5) * step);
    const float hext = (float)(((TS - 1) * 0.5 + 1.0) * step);  // +1px inflation

    // ---- Phase 1: one point per thread, transform + tile-box cull ----
    // (bit-exact round-5 numerics)
    int keep = 0;
    float4 P;
    if (tid < N) {
        const float* pp = points + ((size_t)b * N + tid) * 3;
        float x = pp[0], y = pp[1], z = pp[2];
        float vx = ((x * M1[0] + y * M1[4]) + z * M1[8])  + M1[12];
        float vy = ((x * M1[1] + y * M1[5]) + z * M1[9])  + M1[13];
        float vz = ((x * M1[2] + y * M1[6]) + z * M1[10]) + M1[14];
        float vw = ((x * M1[3] + y * M1[7]) + z * M1[11]) + M1[15];
        float w1 = (fabsf(vw) < 1e-8f) ? 1e-8f : vw;
        vx /= w1; vy /= w1; vz /= w1;
        float sx = ((vx * M2[0] + vy * M2[4]) + vz * M2[8])  + M2[12];
        float sy = ((vx * M2[1] + vy * M2[5]) + vz * M2[9])  + M2[13];
        float sw = ((vx * M2[3] + vy * M2[7]) + vz * M2[11]) + M2[15];
        float w2 = (fabsf(sw) < 1e-8f) ? 1e-8f : sw;
        sx /= w2; sy /= w2;
        float r = radius[(size_t)b * N + tid];
        float r2eff = (vz > 0.0f) ? r * r : -1.0f;
        float dxm = fmaxf(0.0f, fabsf(sx - cx) - hext);
        float dym = fmaxf(0.0f, fabsf(sy - cy) - hext);
        float dmin2 = dxm * dxm + dym * dym;
        keep = (dmin2 <= r2eff + 1e-6f) ? 1 : 0;
        P = make_float4(sx, sy, vz, r2eff);
    }

    // ---- order-preserving compaction via ballot (1 pt/thread) ----
    unsigned long long bmask = __ballot(keep);
    int wcnt = __popcll(bmask);
    int pinc = __popcll(bmask & ((2ULL << lane) - 1));   // inclusive prefix
    if (lane == 0) wsum[wid] = wcnt;
    __syncthreads();
    int wbase = 0, M = 0;
#pragma unroll
    for (int w = 0; w < 16; ++w) {
        int s = wsum[w];
        if (w < wid) wbase += s;
        M += s;
    }
    if (keep) {
        int pos = wbase + pinc - 1;
        cmp[pos]  = P;
        cidx[pos] = tid;
    }
    const int Mpad = (M + 63) & ~63;        // multiple of 64 -> Q multiple of 16
    if (tid < Mpad - M) {
        cmp[M + tid]  = make_float4(0.0f, 0.0f, 0.0f, -1.0f);  // never inside
        cidx[M + tid] = -1;
    }
    __syncthreads();

    // ---- Phase 2: each slice scans its contiguous quarter (dbuf 8-wide) ----
    float zb[KPP]; int id[KPP]; float dd[KPP];
#pragma unroll
    for (int k = 0; k < KPP; ++k) { zb[k] = INFINITY; id[k] = -1; dd[k] = -1.0f; }

    auto process = [&](const float4* pq, const int* ii) {
#pragma unroll
        for (int u = 0; u < 8; ++u) {
            float dx = pq[u].x - px;
            float dy = pq[u].y - py;
            float dist2 = __fadd_rn(__fmul_rn(dx, dx), __fmul_rn(dy, dy));
            if ((dist2 <= pq[u].w) && (pq[u].z < zb[KPP - 1])) {
                float zc = pq[u].z; int ic = ii[u]; float dc = dist2;
#pragma unroll
                for (int k2 = 0; k2 < KPP; ++k2) {
                    bool lt = (zc < zb[k2]);
                    float tz = zb[k2]; int ti = id[k2]; float td = dd[k2];
                    if (lt) { zb[k2] = zc; id[k2] = ic; dd[k2] = dc; zc = tz; ic = ti; dc = td; }
                }
            }
        }
    };

    const int Q    = Mpad >> 2;
    const int base = sl * Q;
    if (Q > 0) {
        float4 pa[8]; int ia[8];
        float4 pb[8]; int ib[8];
#pragma unroll
        for (int u = 0; u < 8; ++u) pa[u] = cmp[base + u];
        {
            int4 a = *(const int4*)&cidx[base];
            int4 c2 = *(const int4*)&cidx[base + 4];
            ia[0]=a.x; ia[1]=a.y; ia[2]=a.z; ia[3]=a.w;
            ia[4]=c2.x; ia[5]=c2.y; ia[6]=c2.z; ia[7]=c2.w;
        }
        for (int n = base; n < base + Q; n += 16) {
#pragma unroll
            for (int u = 0; u < 8; ++u) pb[u] = cmp[n + 8 + u];
            {
                int4 a = *(const int4*)&cidx[n + 8];
                int4 c2 = *(const int4*)&cidx[n + 12];
                ib[0]=a.x; ib[1]=a.y; ib[2]=a.z; ib[3]=a.w;
                ib[4]=c2.x; ib[5]=c2.y; ib[6]=c2.z; ib[7]=c2.w;
            }
            process(pa, ia);
            if (n + 16 < base + Q) {
#pragma unroll
                for (int u = 0; u < 8; ++u) pa[u] = cmp[n + 16 + u];
                int4 a = *(const int4*)&cidx[n + 16];
                int4 c2 = *(const int4*)&cidx[n + 20];
                ia[0]=a.x; ia[1]=a.y; ia[2]=a.z; ia[3]=a.w;
                ia[4]=c2.x; ia[5]=c2.y; ia[6]=c2.z; ia[7]=c2.w;
            }
            process(pb, ib);
        }
    }
    __syncthreads();   // all scans done; cmp/cidx dead from here

    // ---- Merge: slices 1..3 publish top-8; slice 0 inserts (wave-uniform) ----
    for (int ss = 1; ss < 4; ++ss) {
        if (sl == ss) {
#pragma unroll
            for (int k = 0; k < KPP; ++k) {
                mz[k * 256 + p] = zb[k];
                mi[k * 256 + p] = id[k];
                md[k * 256 + p] = dd[k];
            }
        }
        __syncthreads();
        if (sl == 0) {
            float rz[KPP]; int ri[KPP]; float rd[KPP];
#pragma unroll
            for (int k = 0; k < KPP; ++k) {
                rz[k] = mz[k * 256 + p];
                ri[k] = mi[k * 256 + p];
                rd[k] = md[k * 256 + p];
            }
#pragma unroll
            for (int k = 0; k < KPP; ++k) {
                float zc = rz[k]; int ic = ri[k]; float dc = rd[k];
                if (zc < zb[KPP - 1]) {       // INF candidates skipped
#pragma unroll
                    for (int k2 = 0; k2 < KPP; ++k2) {
                        bool lt = (zc < zb[k2]);
                        float tz = zb[k2]; int ti = id[k2]; float td = dd[k2];
                        if (lt) { zb[k2] = zc; id[k2] = ic; dd[k2] = dc; zc = tz; ic = ti; dc = td; }
                    }
                }
            }
        }
        __syncthreads();
    }

    // ---- Phase 3: slice 0 writes outputs ----
    if (sl == 0) {
        const size_t pix   = ((size_t)b * H + i) * W + j;
        const size_t plane = (size_t)B * H * W * KPP;
        float vidx[KPP], vzbf[KPP], vdst[KPP];
#pragma unroll
        for (int k = 0; k < KPP; ++k) {
            bool valid = (zb[k] != INFINITY);
            vidx[k] = valid ? (float)id[k] : -1.0f;
            vzbf[k] = valid ? zb[k]        : -1.0f;
            vdst[k] = valid ? dd[k]        : -1.0f;
        }
        float* oidx = out + pix * KPP;
        float* ozbf = out + plane + pix * KPP;
        float* odst = out + 2 * plane + pix * KPP;
        *(float4*)(oidx)     = make_float4(vidx[0], vidx[1], vidx[2], vidx[3]);
        *(float4*)(oidx + 4) = make_float4(vidx[4], vidx[5], vidx[6], vidx[7]);
        *(float4*)(ozbf)     = make_float4(vzbf[0], vzbf[1], vzbf[2], vzbf[3]);
        *(float4*)(ozbf + 4) = make_float4(vzbf[4], vzbf[5], vzbf[6], vzbf[7]);
        *(float4*)(odst)     = make_float4(vdst[0], vdst[1], vdst[2], vdst[3]);
        *(float4*)(odst + 4) = make_float4(vdst[4], vdst[5], vdst[6], vdst[7]);
    }
}

// Launch-floor probe: same grid/block/LDS shape, ~zero work.
__global__ __launch_bounds__(1024) void floor_probe(float* __restrict__ ws)
{
    if (threadIdx.x == 0) ws[blockIdx.x] = (float)(blockIdx.x + 1);
}

extern "C" void kernel_launch(void* const* d_in, const int* in_sizes, int n_in,
                              void* d_out, int out_size, void* d_ws, size_t ws_size,
                              hipStream_t stream) {
    const float* points = (const float*)d_in[0];
    const float* radius = (const float*)d_in[1];
    const float* w2v    = (const float*)d_in[2];
    const float* proj   = (const float*)d_in[3];
    int B = in_sizes[2] / 16;
    if (B < 1) B = 1;
    int N = in_sizes[1] / B;
    int HW = out_size / (3 * B * KPP);
    int H = 1;
    while ((H + 1) * (H + 1) <= HW) ++H;     // integer sqrt
    int W = H;

    int tiles = (W / TS) * (H / TS);
    size_t shmem = (size_t)(N + 64) * (sizeof(float4) + sizeof(int));
    if (shmem < 24576) shmem = 24576;        // merge buffers

    sphere_raster_kernel<<<B * tiles, 1024, shmem, stream>>>(
        points, radius, w2v, proj, (float*)d_out, B, N, H, W);

    // 4 floor probes (measure launch+ramp F: dur_total = T_main + 4F)
    float* ws = (float*)d_ws;
    floor_probe<<<B * tiles, 1024, shmem, stream>>>(ws);
    floor_probe<<<B * tiles, 1024, shmem, stream>>>(ws);
    floor_probe<<<B * tiles, 1024, shmem, stream>>>(ws);
    floor_probe<<<B * tiles, 1024, shmem, stream>>>(ws);
}

// Round 8
// 15.254 us; speedup vs baseline: 9.1376x; 1.4874x over previous
//
#include <hip/hip_runtime.h>
#include <math.h>

// SpheresRasterizer: B=1, N=1024, H=W=256, K=8.
// Round 8: MINIMAL-CODE-FOOTPRINT variant (i-cache cold-cost theory).
// Algorithm = round 5 (16x16 tiles, inline transform, tile-box cull,
// order-preserving compaction, batched LDS scan), but:
//  - phase 1 is a forced-no-unroll runtime loop staging to LDS (sh[]),
//    keep-bits in a scalar mask (no register arrays -> no scratch);
//  - phase 2 is single-buffered batch-4 (4 insertion copies, not 16+);
//  - single dispatch, no probes.
// Numerics and candidate processing order byte-identical to round 5.

#define KPP 8
#define TS  16

__global__ __launch_bounds__(256) void sphere_raster_kernel(
    const float* __restrict__ points,   // B*N*3
    const float* __restrict__ radius,   // B*N
    const float* __restrict__ w2v,      // B*16
    const float* __restrict__ proj,     // B*16
    float* __restrict__ out,            // 3 * B*H*W*KPP floats
    int B, int N, int H, int W)
{
    extern __shared__ char smem[];
    float4* sh   = (float4*)smem;                                  // N staging
    float4* cmp  = (float4*)(smem + (size_t)N * 16);               // N+8
    int*    cidx = (int*)(smem + (size_t)N * 16 + (size_t)(N + 8) * 16);
    __shared__ int wsum[4];

    const int tid      = threadIdx.x;
    const int tilesX   = W / TS;
    const int tilesPer = tilesX * (H / TS);
    const int tile     = blockIdx.x % tilesPer;
    const int b        = blockIdx.x / tilesPer;
    const int tx0      = (tile % tilesX) * TS;
    const int ty0      = (tile / tilesX) * TS;
    const int j        = tx0 + (tid & (TS - 1));
    const int i        = ty0 + (tid >> 4);
    const int lane     = tid & 63;
    const int wid      = tid >> 6;

    const float* M1 = w2v  + (size_t)b * 16;
    const float* M2 = proj + (size_t)b * 16;

    const double halfd = 1.0 - 1.0 / (double)W;
    const double stepd = 2.0 * halfd / (double)(W - 1);
    const float px = (float)(halfd - (double)j * stepd);
    const float py = (float)(halfd - (double)i * stepd);
    const float cx = (float)(halfd - ((double)tx0 + (TS - 1) * 0.5) * stepd);
    const float cy = (float)(halfd - ((double)ty0 + (TS - 1) * 0.5) * stepd);
    const float hext = (float)(((TS - 1) * 0.5 + 1.0) * stepd);  // +1px inflation

    // ---- Phase 1: transform 4 points/thread (runtime loop, LDS staging) ----
    const int t0 = tid * 4;
    int mask = 0, c = 0;
#pragma unroll 1
    for (int s = 0; s < 4; ++s) {
        const int t = t0 + s;
        const float* pp = points + ((size_t)b * N + t) * 3;
        float x = pp[0], y = pp[1], z = pp[2];
        float vx = ((x * M1[0] + y * M1[4]) + z * M1[8])  + M1[12];
        float vy = ((x * M1[1] + y * M1[5]) + z * M1[9])  + M1[13];
        float vz = ((x * M1[2] + y * M1[6]) + z * M1[10]) + M1[14];
        float vw = ((x * M1[3] + y * M1[7]) + z * M1[11]) + M1[15];
        float w1 = (fabsf(vw) < 1e-8f) ? 1e-8f : vw;
        vx /= w1; vy /= w1; vz /= w1;
        float sx = ((vx * M2[0] + vy * M2[4]) + vz * M2[8])  + M2[12];
        float sy = ((vx * M2[1] + vy * M2[5]) + vz * M2[9])  + M2[13];
        float sw = ((vx * M2[3] + vy * M2[7]) + vz * M2[11]) + M2[15];
        float w2 = (fabsf(sw) < 1e-8f) ? 1e-8f : sw;
        sx /= w2; sy /= w2;
        float r = radius[(size_t)b * N + t];
        float r2eff = (vz > 0.0f) ? r * r : -1.0f;
        sh[t] = make_float4(sx, sy, vz, r2eff);
        float dxm = fmaxf(0.0f, fabsf(sx - cx) - hext);
        float dym = fmaxf(0.0f, fabsf(sy - cy) - hext);
        float dmin2 = dxm * dxm + dym * dym;
        int keep = (dmin2 <= r2eff + 1e-6f) ? 1 : 0;
        mask |= keep << s;
        c += keep;
    }

    // ---- order-preserving compaction (wave scan + block offsets) ----
    int pre = c;
#pragma unroll
    for (int d = 1; d < 64; d <<= 1) {
        int v = __shfl_up(pre, d);
        if (lane >= d) pre += v;
    }
    if (lane == 63) wsum[wid] = pre;
    __syncthreads();
    int wbase = 0, M = 0;
#pragma unroll
    for (int w = 0; w < 4; ++w) {
        int s = wsum[w];
        if (w < wid) wbase += s;
        M += s;
    }
    int pos = wbase + (pre - c);
#pragma unroll 1
    for (int s = 0; s < 4; ++s) {
        if ((mask >> s) & 1) { cmp[pos] = sh[t0 + s]; cidx[pos] = t0 + s; ++pos; }
    }
    const int Mpad = (M + 3) & ~3;
    if (tid < Mpad - M) {
        cmp[M + tid]  = make_float4(0.0f, 0.0f, 0.0f, -1.0f);  // never inside
        cidx[M + tid] = -1;
    }
    __syncthreads();

    // ---- Phase 2: single-buffered batch-4 scan ----
    float zb[KPP]; int id[KPP]; float dd[KPP];
#pragma unroll
    for (int k = 0; k < KPP; ++k) { zb[k] = INFINITY; id[k] = -1; dd[k] = -1.0f; }

    auto test1 = [&](float4 p, int ic0) {
        float dx = p.x - px;
        float dy = p.y - py;
        float dist2 = __fadd_rn(__fmul_rn(dx, dx), __fmul_rn(dy, dy));
        if ((dist2 <= p.w) && (p.z < zb[KPP - 1])) {
            float zc = p.z; int ic = ic0; float dc = dist2;
#pragma unroll
            for (int k2 = 0; k2 < KPP; ++k2) {
                bool lt = (zc < zb[k2]);
                float tz = zb[k2]; int ti = id[k2]; float td = dd[k2];
                if (lt) { zb[k2] = zc; id[k2] = ic; dd[k2] = dc; zc = tz; ic = ti; dc = td; }
            }
        }
    };

#pragma unroll 1
    for (int n = 0; n < Mpad; n += 4) {
        float4 p0 = cmp[n], p1 = cmp[n + 1], p2 = cmp[n + 2], p3 = cmp[n + 3];
        int4 i4 = *(const int4*)&cidx[n];
        test1(p0, i4.x);
        test1(p1, i4.y);
        test1(p2, i4.z);
        test1(p3, i4.w);
    }

    // ---- Phase 3: write outputs ----
    const size_t pix   = ((size_t)b * H + i) * W + j;
    const size_t plane = (size_t)B * H * W * KPP;
    float vidx[KPP], vzbf[KPP], vdst[KPP];
#pragma unroll
    for (int k = 0; k < KPP; ++k) {
        bool valid = (zb[k] != INFINITY);
        vidx[k] = valid ? (float)id[k] : -1.0f;
        vzbf[k] = valid ? zb[k]        : -1.0f;
        vdst[k] = valid ? dd[k]        : -1.0f;
    }
    float* oidx = out + pix * KPP;
    float* ozbf = out + plane + pix * KPP;
    float* odst = out + 2 * plane + pix * KPP;
    *(float4*)(oidx)     = make_float4(vidx[0], vidx[1], vidx[2], vidx[3]);
    *(float4*)(oidx + 4) = make_float4(vidx[4], vidx[5], vidx[6], vidx[7]);
    *(float4*)(ozbf)     = make_float4(vzbf[0], vzbf[1], vzbf[2], vzbf[3]);
    *(float4*)(ozbf + 4) = make_float4(vzbf[4], vzbf[5], vzbf[6], vzbf[7]);
    *(float4*)(odst)     = make_float4(vdst[0], vdst[1], vdst[2], vdst[3]);
    *(float4*)(odst + 4) = make_float4(vdst[4], vdst[5], vdst[6], vdst[7]);
}

extern "C" void kernel_launch(void* const* d_in, const int* in_sizes, int n_in,
                              void* d_out, int out_size, void* d_ws, size_t ws_size,
                              hipStream_t stream) {
    const float* points = (const float*)d_in[0];
    const float* radius = (const float*)d_in[1];
    const float* w2v    = (const float*)d_in[2];
    const float* proj   = (const float*)d_in[3];
    int B = in_sizes[2] / 16;
    if (B < 1) B = 1;
    int N = in_sizes[1] / B;
    int HW = out_size / (3 * B * KPP);
    int H = 1;
    while ((H + 1) * (H + 1) <= HW) ++H;     // integer sqrt
    int W = H;

    int tiles = (W / TS) * (H / TS);
    // LDS: sh (N*16) + cmp ((N+8)*16) + cidx ((N+8)*4)
    size_t shmem = (size_t)N * 16 + (size_t)(N + 8) * 16 + (size_t)(N + 8) * 4;
    sphere_raster_kernel<<<B * tiles, 256, shmem, stream>>>(
        points, radius, w2v, proj, (float*)d_out, B, N, H, W);
}

// Round 9
// 14.748 us; speedup vs baseline: 9.4512x; 1.0343x over previous
//
#include <hip/hip_runtime.h>
#include <math.h>

// SpheresRasterizer: B=1, N=1024, H=W=256, K=8.
// Round 9: per-tile z-SORTED candidate scan.
//  - Phase 1 (unchanged R5 numerics): transform + tile-box cull + compaction.
//  - Wave 0 bitonic-sorts the <=64 candidates by (z, idx) across lanes
//    (exactly lax.top_k's stable ascending-z order, ties by index).
//  - Each pixel scans sorted candidates, appends first 8 that cover it,
//    storing directly to global (no insertion sort), wave early-exit when
//    all 64 pixels are full.
//  - M > 64 fallback: R8-style insertion scan (never taken for this input).

#define KPP 8
#define TS  16

__global__ __launch_bounds__(256) void sphere_raster_kernel(
    const float* __restrict__ points,   // B*N*3
    const float* __restrict__ radius,   // B*N
    const float* __restrict__ w2v,      // B*16
    const float* __restrict__ proj,     // B*16
    float* __restrict__ out,            // 3 * B*H*W*KPP floats
    int B, int N, int H, int W)
{
    extern __shared__ char smem[];
    float4* cmp  = (float4*)smem;                                   // N+64
    int*    cidx = (int*)(smem + (size_t)(N + 64) * 16);            // N+64
    float4* srt  = (float4*)(smem + (size_t)(N + 64) * 20);         // 64
    int*    sidx = (int*)(smem + (size_t)(N + 64) * 20 + 1024);     // 64
    __shared__ int wsum[4];

    const int tid      = threadIdx.x;
    const int tilesX   = W / TS;
    const int tilesPer = tilesX * (H / TS);
    const int tile     = blockIdx.x % tilesPer;
    const int b        = blockIdx.x / tilesPer;
    const int tx0      = (tile % tilesX) * TS;
    const int ty0      = (tile / tilesX) * TS;
    const int j        = tx0 + (tid & (TS - 1));
    const int i        = ty0 + (tid >> 4);
    const int lane     = tid & 63;
    const int wid      = tid >> 6;

    const float* M1 = w2v  + (size_t)b * 16;
    const float* M2 = proj + (size_t)b * 16;

    const double halfd = 1.0 - 1.0 / (double)W;
    const double stepd = 2.0 * halfd / (double)(W - 1);
    const float px = (float)(halfd - (double)j * stepd);
    const float py = (float)(halfd - (double)i * stepd);
    const float cx = (float)(halfd - ((double)tx0 + (TS - 1) * 0.5) * stepd);
    const float cy = (float)(halfd - ((double)ty0 + (TS - 1) * 0.5) * stepd);
    const float hext = (float)(((TS - 1) * 0.5 + 1.0) * stepd);  // +1px inflation

    // ---- Phase 1: transform 4 points/thread, cull to tile box (R5-exact) ----
    const int t0 = tid * 4;
    float4 P[4];
    int keep[4];
    int c = 0;

    const float4* pv = (const float4*)(points + ((size_t)b * N + t0) * 3);
    float4 q0 = pv[0], q1 = pv[1], q2 = pv[2];
    float4 rr = *(const float4*)(radius + (size_t)b * N + t0);
    float xs[4] = {q0.x, q0.w, q1.z, q2.y};
    float ys[4] = {q0.y, q1.x, q1.w, q2.z};
    float zs[4] = {q0.z, q1.y, q2.x, q2.w};
    float rv[4] = {rr.x, rr.y, rr.z, rr.w};

#pragma unroll
    for (int s = 0; s < 4; ++s) {
        float x = xs[s], y = ys[s], z = zs[s];
        float vx = ((x * M1[0] + y * M1[4]) + z * M1[8])  + M1[12];
        float vy = ((x * M1[1] + y * M1[5]) + z * M1[9])  + M1[13];
        float vz = ((x * M1[2] + y * M1[6]) + z * M1[10]) + M1[14];
        float vw = ((x * M1[3] + y * M1[7]) + z * M1[11]) + M1[15];
        float w1 = (fabsf(vw) < 1e-8f) ? 1e-8f : vw;
        vx /= w1; vy /= w1; vz /= w1;
        float sx = ((vx * M2[0] + vy * M2[4]) + vz * M2[8])  + M2[12];
        float sy = ((vx * M2[1] + vy * M2[5]) + vz * M2[9])  + M2[13];
        float sw = ((vx * M2[3] + vy * M2[7]) + vz * M2[11]) + M2[15];
        float w2 = (fabsf(sw) < 1e-8f) ? 1e-8f : sw;
        sx /= w2; sy /= w2;
        float r = rv[s];
        float r2eff = (vz > 0.0f) ? r * r : -1.0f;
        float dxm = fmaxf(0.0f, fabsf(sx - cx) - hext);
        float dym = fmaxf(0.0f, fabsf(sy - cy) - hext);
        float dmin2 = dxm * dxm + dym * dym;
        keep[s] = (dmin2 <= r2eff + 1e-6f) ? 1 : 0;
        P[s] = make_float4(sx, sy, vz, r2eff);
        c += keep[s];
    }

    // ---- order-preserving compaction ----
    int pre = c;
#pragma unroll
    for (int d = 1; d < 64; d <<= 1) {
        int v = __shfl_up(pre, d);
        if (lane >= d) pre += v;
    }
    if (lane == 63) wsum[wid] = pre;
    __syncthreads();
    int wbase = 0, M = 0;
#pragma unroll
    for (int w = 0; w < 4; ++w) {
        int s = wsum[w];
        if (w < wid) wbase += s;
        M += s;
    }
    int pos = wbase + (pre - c);
#pragma unroll
    for (int s = 0; s < 4; ++s) {
        if (keep[s]) { cmp[pos] = P[s]; cidx[pos] = t0 + s; ++pos; }
    }
    // pad: to 64 (sort path) or to multiple of 4 (fallback); z=+INF sorts last,
    // r2=-1 => never inside either way
    const int padTo = (M <= 64) ? 64 : ((M + 3) & ~3);
    if (tid < padTo - M) {
        cmp[M + tid]  = make_float4(0.0f, 0.0f, INFINITY, -1.0f);
        cidx[M + tid] = 0x7fffffff;
    }
    __syncthreads();

    const size_t pix   = ((size_t)b * H + i) * W + j;
    const size_t plane = (size_t)B * H * W * KPP;
    float* oidx = out + pix * KPP;
    float* ozbf = out + plane + pix * KPP;
    float* odst = out + 2 * plane + pix * KPP;

    if (M <= 64) {
        // ---- wave 0: bitonic sort 64 records by (z, idx) across lanes ----
        if (wid == 0) {
            float z  = cmp[lane].z;
            int   k2 = cidx[lane];
            int   sl = lane;
#pragma unroll
            for (int k = 2; k <= 64; k <<= 1) {
#pragma unroll
                for (int jj = k >> 1; jj > 0; jj >>= 1) {
                    float oz  = __shfl_xor(z, jj);
                    int   ok2 = __shfl_xor(k2, jj);
                    int   osl = __shfl_xor(sl, jj);
                    bool keepMin = ((lane & jj) == 0) == ((lane & k) == 0);
                    bool lt = (z < oz) || (z == oz && k2 < ok2);
                    bool mine = keepMin ? lt : !lt;
                    z  = mine ? z  : oz;
                    k2 = mine ? k2 : ok2;
                    sl = mine ? sl : osl;
                }
            }
            srt[lane]  = cmp[sl];
            sidx[lane] = cidx[sl];
        }
        __syncthreads();

        // ---- scan ascending z: append first 8 covering, stream to global ----
        int cnt = 0;
        for (int n = 0; n < M; n += 8) {
            float4 pr[8];
#pragma unroll
            for (int u = 0; u < 8; ++u) pr[u] = srt[n + u];  // srt[64]: in-bounds
            int4 a4 = *(const int4*)&sidx[n];
            int4 b4 = *(const int4*)&sidx[n + 4];
            int ir[8] = {a4.x, a4.y, a4.z, a4.w, b4.x, b4.y, b4.z, b4.w};
#pragma unroll
            for (int u = 0; u < 8; ++u) {
                float dx = pr[u].x - px;
                float dy = pr[u].y - py;
                float dist2 = __fadd_rn(__fmul_rn(dx, dx), __fmul_rn(dy, dy));
                if ((dist2 <= pr[u].w) && (cnt < KPP)) {
                    oidx[cnt] = (float)ir[u];
                    ozbf[cnt] = pr[u].z;
                    odst[cnt] = dist2;
                    ++cnt;
                }
            }
            if (__all(cnt >= KPP)) break;
        }
#pragma unroll
        for (int k = 0; k < KPP; ++k) {
            if (k >= cnt) { oidx[k] = -1.0f; ozbf[k] = -1.0f; odst[k] = -1.0f; }
        }
        return;
    }

    // ---- Fallback M > 64 (not taken for this input): insertion scan ----
    float zb[KPP]; int id[KPP]; float dd[KPP];
#pragma unroll
    for (int k = 0; k < KPP; ++k) { zb[k] = INFINITY; id[k] = -1; dd[k] = -1.0f; }

    auto test1 = [&](float4 p, int ic0) {
        float dx = p.x - px;
        float dy = p.y - py;
        float dist2 = __fadd_rn(__fmul_rn(dx, dx), __fmul_rn(dy, dy));
        if ((dist2 <= p.w) && (p.z < zb[KPP - 1])) {
            float zc = p.z; int ic = ic0; float dc = dist2;
#pragma unroll
            for (int k2 = 0; k2 < KPP; ++k2) {
                bool lt = (zc < zb[k2]);
                float tz = zb[k2]; int ti = id[k2]; float td = dd[k2];
                if (lt) { zb[k2] = zc; id[k2] = ic; dd[k2] = dc; zc = tz; ic = ti; dc = td; }
            }
        }
    };

#pragma unroll 1
    for (int n = 0; n < padTo; n += 4) {
        float4 p0 = cmp[n], p1 = cmp[n + 1], p2 = cmp[n + 2], p3 = cmp[n + 3];
        int4 i4 = *(const int4*)&cidx[n];
        test1(p0, i4.x);
        test1(p1, i4.y);
        test1(p2, i4.z);
        test1(p3, i4.w);
    }

    float vidx[KPP], vzbf[KPP], vdst[KPP];
#pragma unroll
    for (int k = 0; k < KPP; ++k) {
        bool valid = (zb[k] != INFINITY);
        vidx[k] = valid ? (float)id[k] : -1.0f;
        vzbf[k] = valid ? zb[k]        : -1.0f;
        vdst[k] = valid ? dd[k]        : -1.0f;
    }
    *(float4*)(oidx)     = make_float4(vidx[0], vidx[1], vidx[2], vidx[3]);
    *(float4*)(oidx + 4) = make_float4(vidx[4], vidx[5], vidx[6], vidx[7]);
    *(float4*)(ozbf)     = make_float4(vzbf[0], vzbf[1], vzbf[2], vzbf[3]);
    *(float4*)(ozbf + 4) = make_float4(vzbf[4], vzbf[5], vzbf[6], vzbf[7]);
    *(float4*)(odst)     = make_float4(vdst[0], vdst[1], vdst[2], vdst[3]);
    *(float4*)(odst + 4) = make_float4(vdst[4], vdst[5], vdst[6], vdst[7]);
}

extern "C" void kernel_launch(void* const* d_in, const int* in_sizes, int n_in,
                              void* d_out, int out_size, void* d_ws, size_t ws_size,
                              hipStream_t stream) {
    const float* points = (const float*)d_in[0];
    const float* radius = (const float*)d_in[1];
    const float* w2v    = (const float*)d_in[2];
    const float* proj   = (const float*)d_in[3];
    int B = in_sizes[2] / 16;
    if (B < 1) B = 1;
    int N = in_sizes[1] / B;
    int HW = out_size / (3 * B * KPP);
    int H = 1;
    while ((H + 1) * (H + 1) <= HW) ++H;     // integer sqrt
    int W = H;

    int tiles = (W / TS) * (H / TS);
    // LDS: cmp (N+64)*16 + cidx (N+64)*4 + srt 64*16 + sidx 64*4
    size_t shmem = (size_t)(N + 64) * 20 + 64 * 20;
    sphere_raster_kernel<<<B * tiles, 256, shmem, stream>>>(
        points, radius, w2v, proj, (float*)d_out, B, N, H, W);
}